// Round 5
// baseline (10814.128 us; speedup 1.0000x reference)
//
#include <hip/hip_runtime.h>

// ---------------------------------------------------------------------------
// 2-layer GRU (B=64, T=1024, D=256, H=512) + dense head, persistent-RNN style.
// Identical data path to the proven R3 kernel (fp16 MFMA, W_h in LDS, W_i in
// registers, agent-scope atomic exchange through MALL). ONE change: the grid
// barrier's 64 flags now live in a single 64-byte line (1 byte per wg, step
// count mod 256 — skew <= 5 so wraparound-safe). Consumers poll with 16 lanes
// x one u32 + s_sleep backoff instead of 64 lanes x 64 scattered lines:
// ~256x less poll traffic. Split thresholds let L0/L1 run decoupled by the
// h/y double buffers: L0@t waits {L0>=t, L1>=t-1}; L1@t waits {L0>=t+1, L1>=t}.
// ---------------------------------------------------------------------------

#define T_STEPS 1024
#define NWG_TOT 64

typedef _Float16 f16x8 __attribute__((ext_vector_type(8)));
typedef float    f32x4 __attribute__((ext_vector_type(4)));

// ws layout (bytes):
//   0      h0[2][64][512] f16   (131072)
//   131072 h1[2][64][512] f16   (131072)
//   262144 y0[2][64][512] f16   (131072)
//   393216 flag line: 64 bytes, byte i = completed steps of wg i (mod 256)
#define H0_OFF   0
#define H1_OFF   131072
#define Y0_OFF   262144
#define FLAG_OFF 393216
#define WS_ZERO  (393216 + 64)

__device__ __forceinline__ float sigm_f(float x) { return 1.0f / (1.0f + __expf(-x)); }
__device__ __forceinline__ float tanh_f(float x) { return 2.0f / (1.0f + __expf(-2.0f * x)) - 1.0f; }

__device__ __forceinline__ f32x4 mfma16(f16x8 a, f16x8 b, f32x4 c) {
    return __builtin_amdgcn_mfma_f32_16x16x32_f16(a, b, c, 0, 0, 0);
}

__device__ __forceinline__ f16x8 pack8(const float* __restrict__ src, int stride) {
    f16x8 r;
#pragma unroll
    for (int j = 0; j < 8; ++j) r[j] = (_Float16)src[j * stride];
    return r;
}

// device-coherent 16B fragment load as 2x8B relaxed agent atomics (R3-proven)
__device__ __forceinline__ f16x8 ld_frag_dev(const _Float16* p) {
    union { unsigned long long u[2]; f16x8 f; } cvt;
    cvt.u[0] = __hip_atomic_load((const unsigned long long*)p,
                                 __ATOMIC_RELAXED, __HIP_MEMORY_SCOPE_AGENT);
    cvt.u[1] = __hip_atomic_load((const unsigned long long*)(p + 4),
                                 __ATOMIC_RELAXED, __HIP_MEMORY_SCOPE_AGENT);
    return cvt.f;
}

// device-coherent f16 store (R3-proven)
__device__ __forceinline__ void st_dev_f16(_Float16* p, float v) {
    unsigned short b = __builtin_bit_cast(unsigned short, (_Float16)v);
    __hip_atomic_store((unsigned short*)p, b, __ATOMIC_RELAXED, __HIP_MEMORY_SCOPE_AGENT);
}

// producer: drain data stores to the coherence point, wg-sync, post byte flag.
__device__ __forceinline__ void arrive(unsigned char* flagb, int role, int done) {
    asm volatile("s_waitcnt vmcnt(0)" ::: "memory");
    __syncthreads();
    if (threadIdx.x == 0)
        __hip_atomic_store(flagb + role, (unsigned char)(done & 0xFF),
                           __ATOMIC_RELAXED, __HIP_MEMORY_SCOPE_AGENT);
}

// consumer: wave0 lanes 0-15 each poll one u32 of the single flag line.
// bytes 0-31 (lanes 0-7) must be >= e0 (L0 flags); bytes 32-63 (lanes 8-15)
// must be >= e1 (L1 flags). Wraparound-safe: diff mod 256 < 128 == "ahead".
__device__ __forceinline__ void poll(const unsigned* flag32, int e0, int e1,
                                     int wave, int lane) {
    if (wave == 0) {
        const bool active = lane < 16;
        const unsigned eb = (unsigned)(((lane < 8) ? e0 : e1) & 0xFF);
        const unsigned* p = flag32 + (lane & 15);
        for (;;) {
            bool ok = true;
            if (active) {
                unsigned v = __hip_atomic_load(p, __ATOMIC_RELAXED, __HIP_MEMORY_SCOPE_AGENT);
#pragma unroll
                for (int k = 0; k < 4; ++k) {
                    unsigned d = (((v >> (8 * k)) & 0xFFu) - eb) & 0xFFu;
                    ok &= (d < 0x80u);
                }
            }
            if (__all(ok)) break;
            __builtin_amdgcn_s_sleep(1);
        }
    }
    __syncthreads();
}

__global__ __launch_bounds__(256, 1) void gru_scan(
    const float* __restrict__ x,     // [64,1024,256]
    const float* __restrict__ Wi0, const float* __restrict__ bi0,
    const float* __restrict__ Wh0, const float* __restrict__ bhn0,
    const float* __restrict__ Wi1, const float* __restrict__ bi1,
    const float* __restrict__ Wh1, const float* __restrict__ bhn1,
    float* __restrict__ c0_out,      // [64,512]
    float* __restrict__ c1_out,      // [64,512]
    unsigned char* __restrict__ ws)
{
    __shared__ uint4 ldsB[48 * 64];  // 48 KB W_h fragments, frag idx nt*16+kt

    const int tid  = threadIdx.x;
    const int wave = tid >> 6;
    const int lane = tid & 63;
    const int quad = lane >> 4;
    const int l16  = lane & 15;
    const int wg   = blockIdx.x;
    const bool isL1 = (wg >= 32);
    const int role = wg;
    const int cslice = (isL1 ? (wg - 32) : wg) * 16;

    _Float16* h0buf = (_Float16*)(ws + H0_OFF);
    _Float16* h1buf = (_Float16*)(ws + H1_OFF);
    _Float16* y0buf = (_Float16*)(ws + Y0_OFF);
    unsigned char* flagb  = ws + FLAG_OFF;
    const unsigned* flag32 = (const unsigned*)(ws + FLAG_OFF);

    const float* Wh = isL1 ? Wh1 : Wh0;
    const float* Wi = isL1 ? Wi1 : Wi0;

    // ---- stage W_h fragments into LDS ----
    // B-frag (16x16x32): lane holds B[k = kt*32 + quad*8 + j][n = l16]
    for (int f = wave * 12; f < wave * 12 + 12; ++f) {
        int nt = f >> 4, kt = f & 15;
        const float* src = Wh + (kt * 32 + quad * 8) * 1536 + nt * 512 + cslice + l16;
        ldsB[f * 64 + lane] = __builtin_bit_cast(uint4, pack8(src, 1536));
    }

    // ---- W_i fragments in registers ----
    f16x8 wif[48];
    if (!isL1) {
#pragma unroll
        for (int nt = 0; nt < 3; ++nt)
#pragma unroll
            for (int kt = 0; kt < 8; ++kt)
                wif[nt * 8 + kt] = pack8(Wi + (kt * 32 + quad * 8) * 1536 + nt * 512 + cslice + l16, 1536);
    } else {
#pragma unroll
        for (int nt = 0; nt < 3; ++nt)
#pragma unroll
            for (int kt = 0; kt < 16; ++kt)
                wif[nt * 16 + kt] = pack8(Wi + (kt * 32 + quad * 8) * 1536 + nt * 512 + cslice + l16, 1536);
    }

    const float* bi = isL1 ? bi1 : bi0;
    const float* bh = isL1 ? bhn1 : bhn0;
    const float bi_r = bi[cslice + l16];
    const float bi_z = bi[512 + cslice + l16];
    const float bi_n = bi[1024 + cslice + l16];
    const float bhn  = bh[cslice + l16];

    __syncthreads();

    float hstate[4] = {0.f, 0.f, 0.f, 0.f};
    const int rowA = wave * 16 + l16;
    const int rowC = wave * 16 + quad * 4;

    if (!isL1) {
        // ================= layer 0 =================
        for (int t = 0; t < T_STEPS; ++t) {
            // prefetch x[t] (barrier-independent, cached)
            f32x4 xr[16];
            const float* px = x + (size_t)rowA * 262144 + t * 256 + quad * 8;
#pragma unroll
            for (int kt = 0; kt < 8; ++kt) {
                xr[kt * 2]     = *(const f32x4*)(px + kt * 32);
                xr[kt * 2 + 1] = *(const f32x4*)(px + kt * 32 + 4);
            }

            // need: L0 peers done t-1; L1 done t-2 (freed y0 slot t&1)
            poll(flag32, t, (t > 0 ? t - 1 : 0), wave, lane);

            const _Float16* hR = h0buf + (t & 1) * 32768;
            _Float16* hW = h0buf + ((t + 1) & 1) * 32768;
            _Float16* yW = y0buf + (t & 1) * 32768;

            f32x4 ah0 = {0,0,0,0}, ah1 = {0,0,0,0}, ah2 = {0,0,0,0};
            f32x4 ax0 = {0,0,0,0}, ax1 = {0,0,0,0}, ax2 = {0,0,0,0};

#pragma unroll
            for (int kt = 0; kt < 8; ++kt) {
                f32x4 x0 = xr[kt * 2], x1 = xr[kt * 2 + 1];
                f16x8 a;
                a[0] = (_Float16)x0[0]; a[1] = (_Float16)x0[1]; a[2] = (_Float16)x0[2]; a[3] = (_Float16)x0[3];
                a[4] = (_Float16)x1[0]; a[5] = (_Float16)x1[1]; a[6] = (_Float16)x1[2]; a[7] = (_Float16)x1[3];
                ax0 = mfma16(a, wif[0 * 8 + kt], ax0);
                ax1 = mfma16(a, wif[1 * 8 + kt], ax1);
                ax2 = mfma16(a, wif[2 * 8 + kt], ax2);
            }
#pragma unroll
            for (int kt = 0; kt < 16; ++kt) {
                f16x8 a = ld_frag_dev(hR + rowA * 512 + kt * 32 + quad * 8);
                ah0 = mfma16(a, __builtin_bit_cast(f16x8, ldsB[(0 * 16 + kt) * 64 + lane]), ah0);
                ah1 = mfma16(a, __builtin_bit_cast(f16x8, ldsB[(1 * 16 + kt) * 64 + lane]), ah1);
                ah2 = mfma16(a, __builtin_bit_cast(f16x8, ldsB[(2 * 16 + kt) * 64 + lane]), ah2);
            }
#pragma unroll
            for (int i = 0; i < 4; ++i) {
                const int b  = rowC + i;
                const int cu = cslice + l16;
                float r = sigm_f(ax0[i] + bi_r + ah0[i]);
                float z = sigm_f(ax1[i] + bi_z + ah1[i]);
                float n = tanh_f(ax2[i] + bi_n + r * (ah2[i] + bhn));
                float hnew = (1.0f - z) * n + z * hstate[i];
                hstate[i] = hnew;
                st_dev_f16(&hW[b * 512 + cu], hnew);
                st_dev_f16(&yW[b * 512 + cu], tanh_f(hnew));
                if (t == T_STEPS - 1) c0_out[b * 512 + cu] = hnew;
            }
            arrive(flagb, role, t + 1);
        }
    } else {
        // ================= layer 1 =================
        for (int t = 0; t < T_STEPS; ++t) {
            // need: L0 done t (y0[t&1] written); L1 peers done t-1
            poll(flag32, t + 1, t, wave, lane);

            const _Float16* hR = h1buf + (t & 1) * 32768;
            _Float16* hW = h1buf + ((t + 1) & 1) * 32768;
            const _Float16* yR = y0buf + (t & 1) * 32768;

            f32x4 ah0 = {0,0,0,0}, ah1 = {0,0,0,0}, ah2 = {0,0,0,0};
            f32x4 ax0 = {0,0,0,0}, ax1 = {0,0,0,0}, ax2 = {0,0,0,0};

#pragma unroll
            for (int kt = 0; kt < 16; ++kt) {
                f16x8 ah = ld_frag_dev(hR + rowA * 512 + kt * 32 + quad * 8);
                f16x8 ay = ld_frag_dev(yR + rowA * 512 + kt * 32 + quad * 8);
                ah0 = mfma16(ah, __builtin_bit_cast(f16x8, ldsB[(0 * 16 + kt) * 64 + lane]), ah0);
                ah1 = mfma16(ah, __builtin_bit_cast(f16x8, ldsB[(1 * 16 + kt) * 64 + lane]), ah1);
                ah2 = mfma16(ah, __builtin_bit_cast(f16x8, ldsB[(2 * 16 + kt) * 64 + lane]), ah2);
                ax0 = mfma16(ay, wif[0 * 16 + kt], ax0);
                ax1 = mfma16(ay, wif[1 * 16 + kt], ax1);
                ax2 = mfma16(ay, wif[2 * 16 + kt], ax2);
            }
#pragma unroll
            for (int i = 0; i < 4; ++i) {
                const int b  = rowC + i;
                const int cu = cslice + l16;
                float r = sigm_f(ax0[i] + bi_r + ah0[i]);
                float z = sigm_f(ax1[i] + bi_z + ah1[i]);
                float n = tanh_f(ax2[i] + bi_n + r * (ah2[i] + bhn));
                float hnew = (1.0f - z) * n + z * hstate[i];
                hstate[i] = hnew;
                st_dev_f16(&hW[b * 512 + cu], hnew);
                if (t == T_STEPS - 1) c1_out[b * 512 + cu] = hnew;
            }
            arrive(flagb, role, t + 1);
        }
    }
}

// out = tanh(tanh(c1) @ W_out + b_out) : [64,512] @ [512,512], fp32
__global__ __launch_bounds__(256) void dense_out(
    const float* __restrict__ c1, const float* __restrict__ Wout,
    const float* __restrict__ bout, float* __restrict__ out)
{
    __shared__ float a[512];
    const int b = blockIdx.x, tid = threadIdx.x;
    a[tid]       = tanh_f(c1[b * 512 + tid]);
    a[tid + 256] = tanh_f(c1[b * 512 + tid + 256]);
    __syncthreads();
    float acc0 = 0.f, acc1 = 0.f;
#pragma unroll 4
    for (int k = 0; k < 512; ++k) {
        const float av = a[k];
        acc0 += av * Wout[k * 512 + tid];
        acc1 += av * Wout[k * 512 + tid + 256];
    }
    out[b * 512 + tid]       = tanh_f(acc0 + bout[tid]);
    out[b * 512 + tid + 256] = tanh_f(acc1 + bout[tid + 256]);
}

extern "C" void kernel_launch(void* const* d_in, const int* in_sizes, int n_in,
                              void* d_out, int out_size, void* d_ws, size_t ws_size,
                              hipStream_t stream)
{
    const float* x    = (const float*)d_in[0];
    const float* Wi0  = (const float*)d_in[1];
    const float* bi0  = (const float*)d_in[2];
    const float* Wh0  = (const float*)d_in[3];
    const float* bhn0 = (const float*)d_in[4];
    const float* Wi1  = (const float*)d_in[5];
    const float* bi1  = (const float*)d_in[6];
    const float* Wh1  = (const float*)d_in[7];
    const float* bhn1 = (const float*)d_in[8];
    const float* Wout = (const float*)d_in[9];
    const float* bout = (const float*)d_in[10];
    float* out = (float*)d_out;
    unsigned char* ws = (unsigned char*)d_ws;

    // zero h/y double buffers + flag line (ws poisoned 0xAA each launch)
    hipMemsetAsync(ws, 0, WS_ZERO, stream);

    gru_scan<<<NWG_TOT, 256, 0, stream>>>(x, Wi0, bi0, Wh0, bhn0,
                                          Wi1, bi1, Wh1, bhn1,
                                          out + 32768, out + 65536, ws);
    dense_out<<<64, 256, 0, stream>>>(out + 65536, Wout, bout, out);
}